// Round 1
// baseline (235.495 us; speedup 1.0000x reference)
//
#include <hip/hip_runtime.h>
#include <hip/hip_bf16.h>
#include <math.h>

// Problem constants
#define Bn 2
#define Sn 2048
#define Dn 1024
#define Hn 16
#define DKn 64
#define BHS (Bn * Hn * Sn)

using fragb  = __attribute__((ext_vector_type(8))) short;      // 8 bf16
using frag16 = __attribute__((ext_vector_type(8))) _Float16;   // 8 fp16
using f4     = __attribute__((ext_vector_type(4))) float;

__device__ __forceinline__ short f2bf(float f) {
    union { float f; unsigned u; } v; v.f = f;
    unsigned r = v.u + 0x7FFF + ((v.u >> 16) & 1);   // RNE
    return (short)(r >> 16);
}
__device__ __forceinline__ unsigned short f2h(float f) {
    _Float16 h = (_Float16)f;                         // RNE
    unsigned short s; __builtin_memcpy(&s, &h, 2); return s;
}

// async global->LDS, 16B per lane; LDS dest = wave-uniform base + lane*16
#define GLOAD(gptr, lptr)                                                     \
    __builtin_amdgcn_global_load_lds(                                         \
        (const __attribute__((address_space(1))) unsigned int*)(const void*)(gptr), \
        (__attribute__((address_space(3))) unsigned int*)(void*)(lptr), 16, 0, 0)

// ---------------- prep: fp32 -> fp16 casts (x4 vectorized) + bf16 mask row --
#define NX (Bn * Sn * Dn)      // 4M
#define NW (Dn * Dn)           // 1M
#define NF4 ((NX + 4 * NW) / 4)

__global__ __launch_bounds__(256) void prep(
    const float* __restrict__ x,  const float* __restrict__ Wq,
    const float* __restrict__ Wk, const float* __restrict__ Wv,
    const float* __restrict__ Wo, const int* __restrict__ mask,
    short* __restrict__ xh,
    short* __restrict__ Wqh, short* __restrict__ Wkh,
    short* __restrict__ Wvh, short* __restrict__ Woh,
    short* __restrict__ mfb)
{
    int i = blockIdx.x * 256 + threadIdx.x;
    if (i < NF4) {
        int e = i << 2;
        const float* src; short* dst; int j;
        if (e < NX)               { src = x;  dst = xh;  j = e; }
        else if (e < NX + NW)     { src = Wq; dst = Wqh; j = e - NX; }
        else if (e < NX + 2 * NW) { src = Wk; dst = Wkh; j = e - NX - NW; }
        else if (e < NX + 3 * NW) { src = Wv; dst = Wvh; j = e - NX - 2 * NW; }
        else                      { src = Wo; dst = Woh; j = e - NX - 3 * NW; }
        float4 v = *(const float4*)(src + j);
        ushort4 o;
        o.x = f2h(v.x); o.y = f2h(v.y); o.z = f2h(v.z); o.w = f2h(v.w);
        *(ushort4*)(dst + j) = o;
    } else {
        int j = (i - NF4) << 2;
        if (j < Bn * Sn) {
            int4 m = *(const int4*)(mask + j);
            ushort4 o;
            o.x = m.x ? 0x3F80 : 0; o.y = m.y ? 0x3F80 : 0;
            o.z = m.z ? 0x3F80 : 0; o.w = m.w ? 0x3F80 : 0;
            *(ushort4*)(mfb + j) = o;
        }
    }
}

// ---------------- shared GEMM machinery: 128x128 tile, BK=64, dbuf, swizzle -
// LDS physical (row, chunk_phys) holds logical (row, chunk_phys ^ (row&7));
// staged via pre-swizzled global source (linear global_load_lds dest),
// read with the same XOR => 2-way (free) bank access instead of 16-way.

#define STAGE(buf, kk0) do {                                                  \
    const short* _as = Asrc + (kk0);                                          \
    const short* _bs = Bsrc + (kk0);                                          \
    GLOAD(_as,            &As[buf][wave * 512]);                              \
    GLOAD(_as + 32 * Dn,  &As[buf][2048 + wave * 512]);                       \
    GLOAD(_as + 64 * Dn,  &As[buf][4096 + wave * 512]);                       \
    GLOAD(_as + 96 * Dn,  &As[buf][6144 + wave * 512]);                       \
    GLOAD(_bs,            &Bs[buf][wave * 512]);                              \
    GLOAD(_bs + 32 * Dn,  &Bs[buf][2048 + wave * 512]);                       \
    GLOAD(_bs + 64 * Dn,  &Bs[buf][4096 + wave * 512]);                       \
    GLOAD(_bs + 96 * Dn,  &Bs[buf][6144 + wave * 512]);                       \
} while (0)

#define COMPUTE(buf) do {                                                     \
    frag16 _a[2][4], _b[2][4];                                                \
    _Pragma("unroll")                                                         \
    for (int kk = 0; kk < 2; kk++) {                                          \
        _Pragma("unroll")                                                     \
        for (int mi = 0; mi < 4; mi++)                                        \
            _a[kk][mi] = *(const frag16*)&As[buf][                            \
                (wm * 64 + mi * 16 + l16) * 64 +                              \
                (((kk << 2) | quad) ^ (l16 & 7)) * 8];                        \
        _Pragma("unroll")                                                     \
        for (int ni = 0; ni < 4; ni++)                                        \
            _b[kk][ni] = *(const frag16*)&Bs[buf][                            \
                (wn * 64 + ni * 16 + l16) * 64 +                              \
                (((kk << 2) | quad) ^ (l16 & 7)) * 8];                        \
    }                                                                         \
    _Pragma("unroll")                                                         \
    for (int kk = 0; kk < 2; kk++)                                            \
        _Pragma("unroll")                                                     \
        for (int mi = 0; mi < 4; mi++)                                        \
            _Pragma("unroll")                                                 \
            for (int ni = 0; ni < 4; ni++)                                    \
                acc[mi][ni] = __builtin_amdgcn_mfma_f32_16x16x32_f16(         \
                    _a[kk][mi], _b[kk][ni], acc[mi][ni], 0, 0, 0);            \
} while (0)

// ---------------- QKV GEMM: fp16, dbuf 2-phase prefetch, BK=64 --------------
__global__ __launch_bounds__(256) void gemm_qkv(
    const short* __restrict__ A,
    const short* __restrict__ W0, const float* __restrict__ b0,
    const short* __restrict__ W1, const float* __restrict__ b1,
    const short* __restrict__ W2, const float* __restrict__ b2,
    const int* __restrict__ mask,
    short* __restrict__ Qb, short* __restrict__ Kb, short* __restrict__ Vtb)
{
    __shared__ __align__(16) short As[2][128 * 64];
    __shared__ __align__(16) short Bs[2][128 * 64];

    const int tid  = threadIdx.x;
    const int wave = tid >> 6;
    const int lane = tid & 63;
    const int quad = lane >> 4;
    const int l16  = lane & 15;
    const int wm   = wave >> 1;
    const int wn   = wave & 1;

    const int m0   = blockIdx.y * 128;
    const int n0   = blockIdx.x * 128;
    const int widx = n0 >> 10;
    const int nl0  = n0 & 1023;

    const short* Wp   = widx == 0 ? W0 : (widx == 1 ? W1 : W2);
    const float* bias = widx == 0 ? b0 : (widx == 1 ? b1 : b2);

    f4 acc[4][4];
    #pragma unroll
    for (int i = 0; i < 4; i++)
        #pragma unroll
        for (int j = 0; j < 4; j++) {
            acc[i][j][0] = 0.f; acc[i][j][1] = 0.f;
            acc[i][j][2] = 0.f; acc[i][j][3] = 0.f;
        }

    const int sr = tid >> 3;                       // staged row (0..31) per round
    const int sc = ((tid & 7) ^ (sr & 7)) * 8;     // pre-swizzled source chunk
    const short* Asrc = A  + (size_t)(m0  + sr) * Dn + sc;
    const short* Bsrc = Wp + (size_t)(nl0 + sr) * Dn + sc;

    STAGE(0, 0);
    __syncthreads();                                // drains vmcnt(0): buf0 ready
    int cur = 0;
    for (int it = 0; it < 15; ++it) {
        STAGE(cur ^ 1, (it + 1) << 6);              // prefetch next K-tile
        COMPUTE(cur);                               // overlap with HBM latency
        __syncthreads();                            // one drain+barrier per K-tile
        cur ^= 1;
    }
    COMPUTE(cur);

    const float QSCALE = 0.125f * 1.44269504088896340736f;

    #pragma unroll
    for (int mi = 0; mi < 4; mi++) {
        #pragma unroll
        for (int ni = 0; ni < 4; ni++) {
            int nl = nl0 + wn * 64 + ni * 16 + l16;
            float bv = bias[nl];
            #pragma unroll
            for (int r = 0; r < 4; r++) {
                int m = m0 + wm * 64 + mi * 16 + quad * 4 + r;
                float v = acc[mi][ni][r] + bv;
                int b  = m >> 11, s = m & (Sn - 1);
                int h  = nl >> 6, dk = nl & 63;
                if (widx == 0)
                    Qb[((size_t)(b * Hn + h) * Sn + s) * DKn + dk] = f2bf(v * QSCALE);
                else if (widx == 1)
                    Kb[((size_t)(b * Hn + h) * Sn + s) * DKn + dk] = f2bf(v);
                else {
                    float mv = (float)mask[b * Sn + s];
                    Vtb[((size_t)(b * Hn + h) * DKn + dk) * Sn + s] = f2bf(v * mv);
                }
            }
        }
    }
}

// ---------------- Out GEMM: fp16, dbuf 2-phase prefetch, BM=128, fp32 out ---
__global__ __launch_bounds__(256) void gemm_out(
    const short* __restrict__ A, const short* __restrict__ Wp,
    const float* __restrict__ bias, float* __restrict__ outf)
{
    __shared__ __align__(16) short As[2][128 * 64];
    __shared__ __align__(16) short Bs[2][128 * 64];

    const int tid  = threadIdx.x;
    const int wave = tid >> 6;
    const int lane = tid & 63;
    const int quad = lane >> 4;
    const int l16  = lane & 15;
    const int wm   = wave >> 1;
    const int wn   = wave & 1;

    const int m0 = blockIdx.y * 128;
    const int n0 = blockIdx.x * 128;

    f4 acc[4][4];
    #pragma unroll
    for (int i = 0; i < 4; i++)
        #pragma unroll
        for (int j = 0; j < 4; j++) {
            acc[i][j][0] = 0.f; acc[i][j][1] = 0.f;
            acc[i][j][2] = 0.f; acc[i][j][3] = 0.f;
        }

    const int sr = tid >> 3;
    const int sc = ((tid & 7) ^ (sr & 7)) * 8;
    const short* Asrc = A  + (size_t)(m0 + sr) * Dn + sc;
    const short* Bsrc = Wp + (size_t)(n0 + sr) * Dn + sc;

    STAGE(0, 0);
    __syncthreads();
    int cur = 0;
    for (int it = 0; it < 15; ++it) {
        STAGE(cur ^ 1, (it + 1) << 6);
        COMPUTE(cur);
        __syncthreads();
        cur ^= 1;
    }
    COMPUTE(cur);

    #pragma unroll
    for (int mi = 0; mi < 4; mi++) {
        #pragma unroll
        for (int ni = 0; ni < 4; ni++) {
            int nl = n0 + wn * 64 + ni * 16 + l16;
            float bv = bias[nl];
            #pragma unroll
            for (int r = 0; r < 4; r++) {
                int m = m0 + wm * 64 + mi * 16 + quad * 4 + r;
                outf[(size_t)m * Dn + nl] = acc[mi][ni][r] + bv;
            }
        }
    }
}

// ---------------- Flash attention: split-K x2, raw v_exp_f32 softmax --------
#define LP  72

__global__ __launch_bounds__(256) void attn_mfma(
    const short* __restrict__ Qb, const short* __restrict__ Kb,
    const short* __restrict__ Vtb, const short* __restrict__ mfb,
    float* __restrict__ ctxp0, float* __restrict__ ctxp1,
    float* __restrict__ lp)
{
    __shared__ __align__(16) short Ks[64 * 64];
    __shared__ __align__(16) short Vs[64 * 64];
    __shared__ short Ps[4][32 * LP];
    __shared__ __align__(16) short mfs[64];

    const int tid  = threadIdx.x;
    const int wave = tid >> 6;
    const int lane = tid & 63;
    const int quad = lane >> 4;
    const int l16  = lane & 15;

    const int split = blockIdx.x & 1;
    const int rest  = blockIdx.x >> 1;
    const int qt  = rest & 15;
    const int bhh = rest >> 4;
    const int b   = bhh >> 4;
    const int h   = bhh & 15;

    fragb qf[2][2];
    #pragma unroll
    for (int w = 0; w < 2; w++) {
        int qrow = qt * 128 + wave * 32 + w * 16 + l16;
        const short* qptr = Qb + ((size_t)bhh * Sn + qrow) * DKn + quad * 8;
        qf[w][0] = *(const fragb*)(qptr);
        qf[w][1] = *(const fragb*)(qptr + 32);
    }

    f4 ctx[2][4];
    #pragma unroll
    for (int w = 0; w < 2; w++)
        #pragma unroll
        for (int dt = 0; dt < 4; dt++) {
            ctx[w][dt][0] = 0.f; ctx[w][dt][1] = 0.f;
            ctx[w][dt][2] = 0.f; ctx[w][dt][3] = 0.f;
        }
    f4 lacc[2];
    lacc[0][0] = 0.f; lacc[0][1] = 0.f; lacc[0][2] = 0.f; lacc[0][3] = 0.f;
    lacc[1] = lacc[0];

    const int lr = lane >> 3;
    const int sc = ((lane & 7) ^ lr) * 8;
    const short* Kg = Kb  + (size_t)bhh * Sn * DKn;
    const short* Vg = Vtb + (size_t)bhh * DKn * Sn;
    const short* mg = mfb + (size_t)b * Sn;

    const short* Ksrc = Kg + (size_t)(wave * 16 + lr) * DKn + sc;
    const short* Vsrc = Vg + (size_t)(wave * 16 + lr) * Sn + sc;

    const int c0 = ((quad ^ (l16 & 7)) * 8);

    const int kt0 = split * 16;
    for (int kt = kt0; kt < kt0 + 16; kt++) {
        __syncthreads();
        GLOAD(Ksrc + (size_t)kt * 4096,             &Ks[(wave * 16) * 64]);
        GLOAD(Ksrc + (size_t)kt * 4096 + 8 * DKn,   &Ks[(wave * 16 + 8) * 64]);
        GLOAD(Vsrc + (size_t)kt * 64,               &Vs[(wave * 16) * 64]);
        GLOAD(Vsrc + (size_t)kt * 64 + 8 * Sn,      &Vs[(wave * 16 + 8) * 64]);
        if (tid < 8)
            *(uint4*)&mfs[tid * 8] = *(const uint4*)(mg + kt * 64 + tid * 8);
        __syncthreads();

        #pragma unroll
        for (int t = 0; t < 4; t++) {
            fragb k0 = *(const fragb*)&Ks[(t * 16 + l16) * 64 + c0];
            fragb k1 = *(const fragb*)&Ks[(t * 16 + l16) * 64 + (c0 ^ 32)];
            #pragma unroll
            for (int w = 0; w < 2; w++) {
                f4 a; a[0] = 0.f; a[1] = 0.f; a[2] = 0.f; a[3] = 0.f;
                a = __builtin_amdgcn_mfma_f32_16x16x32_bf16(k0, qf[w][0], a, 0, 0, 0);
                a = __builtin_amdgcn_mfma_f32_16x16x32_bf16(k1, qf[w][1], a, 0, 0, 0);
                // raw v_exp_f32 (log2e folded into Q): 1 instr vs OCML's ~8
                unsigned u0 = __float_as_uint(__builtin_amdgcn_exp2f(a[0]));
                unsigned u1 = __float_as_uint(__builtin_amdgcn_exp2f(a[1]));
                unsigned u2 = __float_as_uint(__builtin_amdgcn_exp2f(a[2]));
                unsigned u3 = __float_as_uint(__builtin_amdgcn_exp2f(a[3]));
                uint2 pw;
                pw.x = __builtin_amdgcn_perm(u1, u0, 0x07060302u);
                pw.y = __builtin_amdgcn_perm(u3, u2, 0x07060302u);
                *(uint2*)&Ps[wave][(w * 16 + l16) * LP + 16 * t + quad * 4] = pw;
            }
        }

        fragb p[2][2];
        #pragma unroll
        for (int w = 0; w < 2; w++) {
            p[w][0] = *(const fragb*)&Ps[wave][(w * 16 + l16) * LP + quad * 8];
            p[w][1] = *(const fragb*)&Ps[wave][(w * 16 + l16) * LP + quad * 8 + 32];
        }
        fragb m0 = *(const fragb*)&mfs[quad * 8];
        fragb m1 = *(const fragb*)&mfs[quad * 8 + 32];
        #pragma unroll
        for (int w = 0; w < 2; w++) {
            lacc[w] = __builtin_amdgcn_mfma_f32_16x16x32_bf16(p[w][0], m0, lacc[w], 0, 0, 0);
            lacc[w] = __builtin_amdgcn_mfma_f32_16x16x32_bf16(p[w][1], m1, lacc[w], 0, 0, 0);
        }
        #pragma unroll
        for (int dt = 0; dt < 4; dt++) {
            fragb v0 = *(const fragb*)&Vs[(dt * 16 + l16) * 64 + c0];
            fragb v1 = *(const fragb*)&Vs[(dt * 16 + l16) * 64 + (c0 ^ 32)];
            #pragma unroll
            for (int w = 0; w < 2; w++) {
                ctx[w][dt] = __builtin_amdgcn_mfma_f32_16x16x32_bf16(p[w][0], v0, ctx[w][dt], 0, 0, 0);
                ctx[w][dt] = __builtin_amdgcn_mfma_f32_16x16x32_bf16(p[w][1], v1, ctx[w][dt], 0, 0, 0);
            }
        }
    }

    float* cp  = split ? ctxp1 : ctxp0;
    float* lpp = lp + (size_t)split * BHS;
    #pragma unroll
    for (int w = 0; w < 2; w++)
        #pragma unroll
        for (int r = 0; r < 4; r++) {
            int row = qt * 128 + wave * 32 + w * 16 + quad * 4 + r;
            if (l16 == 0) lpp[(size_t)bhh * Sn + row] = lacc[w][r];
            #pragma unroll
            for (int dt = 0; dt < 4; dt++)
                cp[((size_t)(b * Sn + row)) * Dn + h * DKn + dt * 16 + l16] =
                    ctx[w][dt][r];
        }
}

// ---------------- reduce: merge split partials, normalize, emit fp16 --------
__global__ __launch_bounds__(256) void reduce_ctx(
    const float* __restrict__ c0, const float* __restrict__ c1,
    const float* __restrict__ lp, short* __restrict__ Ch)
{
    int i4 = blockIdx.x * 256 + threadIdx.x;
    int e    = i4 << 2;
    int brow = e >> 10;
    int d    = e & 1023;
    int b    = brow >> 11;
    int row  = brow & (Sn - 1);
    int h    = d >> 6;
    size_t li = (size_t)(b * Hn + h) * Sn + row;
    float l = lp[li] + lp[BHS + li];
    float inv = 1.f / l;
    float4 v0 = ((const float4*)c0)[i4];
    float4 v1 = ((const float4*)c1)[i4];
    ushort4 o;
    o.x = f2h((v0.x + v1.x) * inv);
    o.y = f2h((v0.y + v1.y) * inv);
    o.z = f2h((v0.z + v1.z) * inv);
    o.w = f2h((v0.w + v1.w) * inv);
    ((ushort4*)Ch)[i4] = o;
}

// ---------------- launch ----------------
extern "C" void kernel_launch(void* const* d_in, const int* in_sizes, int n_in,
                              void* d_out, int out_size, void* d_ws, size_t ws_size,
                              hipStream_t stream) {
    const float* x    = (const float*)d_in[0];
    const int*   mask = (const int*)d_in[1];
    const float* Wq   = (const float*)d_in[2];
    const float* bq   = (const float*)d_in[3];
    const float* Wk   = (const float*)d_in[4];
    const float* bk   = (const float*)d_in[5];
    const float* Wv   = (const float*)d_in[6];
    const float* bv   = (const float*)d_in[7];
    const float* Wo   = (const float*)d_in[8];
    const float* bo   = (const float*)d_in[9];
    float* out = (float*)d_out;

    char* ws = (char*)d_ws;
    const size_t MB = 1024u * 1024u;
    short* xh    = (short*)(ws + 0 * MB);    // 8 MB fp16 (dead after QKV)
    short* Wqh   = (short*)(ws + 8 * MB);
    short* Wkh   = (short*)(ws + 10 * MB);
    short* Wvh   = (short*)(ws + 12 * MB);
    short* Qb    = (short*)(ws + 16 * MB);
    short* Kb    = (short*)(ws + 24 * MB);
    short* Vtb   = (short*)(ws + 32 * MB);
    float* ctxp0 = (float*)(ws + 0 * MB);    // overlays dead region
    float* ctxp1 = (float*)(ws + 40 * MB);
    short* Woh   = (short*)(ws + 56 * MB);
    float* lp    = (float*)(ws + 58 * MB);
    short* mfb   = (short*)(ws + 59 * MB);
    short* Ch    = (short*)(ws + 60 * MB);

    const int PRE = NF4 + (Bn * Sn) / 4;
    prep<<<(PRE + 255) / 256, 256, 0, stream>>>(
        x, Wq, Wk, Wv, Wo, mask, xh, Wqh, Wkh, Wvh, Woh, mfb);

    gemm_qkv<<<dim3(24, 32), 256, 0, stream>>>(
        xh, Wqh, bq, Wkh, bk, Wvh, bv, mask, Qb, Kb, Vtb);

    attn_mfma<<<dim3(Bn * Hn * (Sn / 128) * 2), 256, 0, stream>>>(
        Qb, Kb, Vtb, mfb, ctxp0, ctxp1, lp);

    reduce_ctx<<<dim3(NX / 4 / 256), 256, 0, stream>>>(ctxp0, ctxp1, lp, Ch);

    gemm_out<<<dim3(8, 32), 256, 0, stream>>>(Ch, Woh, bo, out);
}

// Round 2
// 229.766 us; speedup vs baseline: 1.0249x; 1.0249x over previous
//
#include <hip/hip_runtime.h>
#include <hip/hip_bf16.h>
#include <math.h>

// Problem constants
#define Bn 2
#define Sn 2048
#define Dn 1024
#define Hn 16
#define DKn 64
#define BHS (Bn * Hn * Sn)

using fragb  = __attribute__((ext_vector_type(8))) short;      // 8 bf16
using frag16 = __attribute__((ext_vector_type(8))) _Float16;   // 8 fp16
using f4     = __attribute__((ext_vector_type(4))) float;

__device__ __forceinline__ short f2bf(float f) {
    union { float f; unsigned u; } v; v.f = f;
    unsigned r = v.u + 0x7FFF + ((v.u >> 16) & 1);   // RNE
    return (short)(r >> 16);
}
__device__ __forceinline__ unsigned short f2h(float f) {
    _Float16 h = (_Float16)f;                         // RNE
    unsigned short s; __builtin_memcpy(&s, &h, 2); return s;
}

// async global->LDS, 16B per lane; LDS dest = wave-uniform base + lane*16
#define GLOAD(gptr, lptr)                                                     \
    __builtin_amdgcn_global_load_lds(                                         \
        (const __attribute__((address_space(1))) unsigned int*)(const void*)(gptr), \
        (__attribute__((address_space(3))) unsigned int*)(void*)(lptr), 16, 0, 0)

// ---------------- prep: fp32 -> fp16 casts (x4 vectorized) + bf16 mask row --
#define NX (Bn * Sn * Dn)      // 4M
#define NW (Dn * Dn)           // 1M
#define NF4 ((NX + 4 * NW) / 4)

__global__ __launch_bounds__(256) void prep(
    const float* __restrict__ x,  const float* __restrict__ Wq,
    const float* __restrict__ Wk, const float* __restrict__ Wv,
    const float* __restrict__ Wo, const int* __restrict__ mask,
    short* __restrict__ xh,
    short* __restrict__ Wqh, short* __restrict__ Wkh,
    short* __restrict__ Wvh, short* __restrict__ Woh,
    short* __restrict__ mfb)
{
    int i = blockIdx.x * 256 + threadIdx.x;
    if (i < NF4) {
        int e = i << 2;
        const float* src; short* dst; int j;
        if (e < NX)               { src = x;  dst = xh;  j = e; }
        else if (e < NX + NW)     { src = Wq; dst = Wqh; j = e - NX; }
        else if (e < NX + 2 * NW) { src = Wk; dst = Wkh; j = e - NX - NW; }
        else if (e < NX + 3 * NW) { src = Wv; dst = Wvh; j = e - NX - 2 * NW; }
        else                      { src = Wo; dst = Woh; j = e - NX - 3 * NW; }
        float4 v = *(const float4*)(src + j);
        ushort4 o;
        o.x = f2h(v.x); o.y = f2h(v.y); o.z = f2h(v.z); o.w = f2h(v.w);
        *(ushort4*)(dst + j) = o;
    } else {
        int j = (i - NF4) << 2;
        if (j < Bn * Sn) {
            int4 m = *(const int4*)(mask + j);
            ushort4 o;
            o.x = m.x ? 0x3F80 : 0; o.y = m.y ? 0x3F80 : 0;
            o.z = m.z ? 0x3F80 : 0; o.w = m.w ? 0x3F80 : 0;
            *(ushort4*)(mfb + j) = o;
        }
    }
}

// ------- shared GEMM machinery: 128x128 tile, BK=64, SINGLE buffer, swizzle -
// m97 structure: 32 KB LDS (multi-block residency does the overlap), 2
// barriers per K-step, 32 MFMA per staging round.
// LDS physical (row, chunk_phys) holds logical (row, chunk_phys ^ (row&7));
// staged via pre-swizzled global source (linear global_load_lds dest),
// read with the same XOR => 2-way (free) bank access instead of 16-way.

#define STAGE(kk0) do {                                                       \
    const short* _as = Asrc + (kk0);                                          \
    const short* _bs = Bsrc + (kk0);                                          \
    GLOAD(_as,            &As[wave * 512]);                                   \
    GLOAD(_as + 32 * Dn,  &As[2048 + wave * 512]);                            \
    GLOAD(_as + 64 * Dn,  &As[4096 + wave * 512]);                            \
    GLOAD(_as + 96 * Dn,  &As[6144 + wave * 512]);                            \
    GLOAD(_bs,            &Bs[wave * 512]);                                   \
    GLOAD(_bs + 32 * Dn,  &Bs[2048 + wave * 512]);                            \
    GLOAD(_bs + 64 * Dn,  &Bs[4096 + wave * 512]);                            \
    GLOAD(_bs + 96 * Dn,  &Bs[6144 + wave * 512]);                            \
} while (0)

#define COMPUTE() do {                                                        \
    frag16 _a[2][4], _b[2][4];                                                \
    _Pragma("unroll")                                                         \
    for (int kk = 0; kk < 2; kk++) {                                          \
        _Pragma("unroll")                                                     \
        for (int mi = 0; mi < 4; mi++)                                        \
            _a[kk][mi] = *(const frag16*)&As[                                 \
                (wm * 64 + mi * 16 + l16) * 64 +                              \
                (((kk << 2) | quad) ^ (l16 & 7)) * 8];                        \
        _Pragma("unroll")                                                     \
        for (int ni = 0; ni < 4; ni++)                                        \
            _b[kk][ni] = *(const frag16*)&Bs[                                 \
                (wn * 64 + ni * 16 + l16) * 64 +                              \
                (((kk << 2) | quad) ^ (l16 & 7)) * 8];                        \
    }                                                                         \
    _Pragma("unroll")                                                         \
    for (int kk = 0; kk < 2; kk++)                                            \
        _Pragma("unroll")                                                     \
        for (int mi = 0; mi < 4; mi++)                                        \
            _Pragma("unroll")                                                 \
            for (int ni = 0; ni < 4; ni++)                                    \
                acc[mi][ni] = __builtin_amdgcn_mfma_f32_16x16x32_f16(         \
                    _a[kk][mi], _b[kk][ni], acc[kk ? mi : mi][ni], 0, 0, 0);  \
} while (0)

// ---------------- QKV GEMM: fp16, m97 structure, BK=64 ----------------------
__global__ __launch_bounds__(256) void gemm_qkv(
    const short* __restrict__ A,
    const short* __restrict__ W0, const float* __restrict__ b0,
    const short* __restrict__ W1, const float* __restrict__ b1,
    const short* __restrict__ W2, const float* __restrict__ b2,
    const int* __restrict__ mask,
    short* __restrict__ Qb, short* __restrict__ Kb, short* __restrict__ Vtb)
{
    __shared__ __align__(16) short As[128 * 64];
    __shared__ __align__(16) short Bs[128 * 64];

    const int tid  = threadIdx.x;
    const int wave = tid >> 6;
    const int lane = tid & 63;
    const int quad = lane >> 4;
    const int l16  = lane & 15;
    const int wm   = wave >> 1;
    const int wn   = wave & 1;

    const int m0   = blockIdx.y * 128;
    const int n0   = blockIdx.x * 128;
    const int widx = n0 >> 10;
    const int nl0  = n0 & 1023;

    const short* Wp   = widx == 0 ? W0 : (widx == 1 ? W1 : W2);
    const float* bias = widx == 0 ? b0 : (widx == 1 ? b1 : b2);

    f4 acc[4][4];
    #pragma unroll
    for (int i = 0; i < 4; i++)
        #pragma unroll
        for (int j = 0; j < 4; j++) {
            acc[i][j][0] = 0.f; acc[i][j][1] = 0.f;
            acc[i][j][2] = 0.f; acc[i][j][3] = 0.f;
        }

    const int sr = tid >> 3;                       // staged row per round
    const int sc = ((tid & 7) ^ (sr & 7)) * 8;     // pre-swizzled source chunk
    const short* Asrc = A  + (size_t)(m0  + sr) * Dn + sc;
    const short* Bsrc = Wp + (size_t)(nl0 + sr) * Dn + sc;

    for (int k0 = 0; k0 < Dn; k0 += 64) {
        __syncthreads();
        STAGE(k0);
        __syncthreads();
        COMPUTE();
    }

    const float QSCALE = 0.125f * 1.44269504088896340736f;

    #pragma unroll
    for (int mi = 0; mi < 4; mi++) {
        #pragma unroll
        for (int ni = 0; ni < 4; ni++) {
            int nl = nl0 + wn * 64 + ni * 16 + l16;
            float bv = bias[nl];
            #pragma unroll
            for (int r = 0; r < 4; r++) {
                int m = m0 + wm * 64 + mi * 16 + quad * 4 + r;
                float v = acc[mi][ni][r] + bv;
                int b  = m >> 11, s = m & (Sn - 1);
                int h  = nl >> 6, dk = nl & 63;
                if (widx == 0)
                    Qb[((size_t)(b * Hn + h) * Sn + s) * DKn + dk] = f2bf(v * QSCALE);
                else if (widx == 1)
                    Kb[((size_t)(b * Hn + h) * Sn + s) * DKn + dk] = f2bf(v);
                else {
                    float mv = (float)mask[b * Sn + s];
                    Vtb[((size_t)(b * Hn + h) * DKn + dk) * Sn + s] = f2bf(v * mv);
                }
            }
        }
    }
}

// ---------------- Out GEMM: fp16, m97 structure, BM=128, fp32 out -----------
__global__ __launch_bounds__(256) void gemm_out(
    const short* __restrict__ A, const short* __restrict__ Wp,
    const float* __restrict__ bias, float* __restrict__ outf)
{
    __shared__ __align__(16) short As[128 * 64];
    __shared__ __align__(16) short Bs[128 * 64];

    const int tid  = threadIdx.x;
    const int wave = tid >> 6;
    const int lane = tid & 63;
    const int quad = lane >> 4;
    const int l16  = lane & 15;
    const int wm   = wave >> 1;
    const int wn   = wave & 1;

    const int m0 = blockIdx.y * 128;
    const int n0 = blockIdx.x * 128;

    f4 acc[4][4];
    #pragma unroll
    for (int i = 0; i < 4; i++)
        #pragma unroll
        for (int j = 0; j < 4; j++) {
            acc[i][j][0] = 0.f; acc[i][j][1] = 0.f;
            acc[i][j][2] = 0.f; acc[i][j][3] = 0.f;
        }

    const int sr = tid >> 3;
    const int sc = ((tid & 7) ^ (sr & 7)) * 8;
    const short* Asrc = A  + (size_t)(m0 + sr) * Dn + sc;
    const short* Bsrc = Wp + (size_t)(n0 + sr) * Dn + sc;

    for (int k0 = 0; k0 < Dn; k0 += 64) {
        __syncthreads();
        STAGE(k0);
        __syncthreads();
        COMPUTE();
    }

    #pragma unroll
    for (int mi = 0; mi < 4; mi++) {
        #pragma unroll
        for (int ni = 0; ni < 4; ni++) {
            int nl = n0 + wn * 64 + ni * 16 + l16;
            float bv = bias[nl];
            #pragma unroll
            for (int r = 0; r < 4; r++) {
                int m = m0 + wm * 64 + mi * 16 + quad * 4 + r;
                outf[(size_t)m * Dn + nl] = acc[mi][ni][r] + bv;
            }
        }
    }
}

// ---------------- Flash attention: split-K x2, raw v_exp_f32 softmax --------
#define LP  72

__global__ __launch_bounds__(256) void attn_mfma(
    const short* __restrict__ Qb, const short* __restrict__ Kb,
    const short* __restrict__ Vtb, const short* __restrict__ mfb,
    float* __restrict__ ctxp0, float* __restrict__ ctxp1,
    float* __restrict__ lp)
{
    __shared__ __align__(16) short Ks[64 * 64];
    __shared__ __align__(16) short Vs[64 * 64];
    __shared__ short Ps[4][32 * LP];
    __shared__ __align__(16) short mfs[64];

    const int tid  = threadIdx.x;
    const int wave = tid >> 6;
    const int lane = tid & 63;
    const int quad = lane >> 4;
    const int l16  = lane & 15;

    const int split = blockIdx.x & 1;
    const int rest  = blockIdx.x >> 1;
    const int qt  = rest & 15;
    const int bhh = rest >> 4;
    const int b   = bhh >> 4;
    const int h   = bhh & 15;

    fragb qf[2][2];
    #pragma unroll
    for (int w = 0; w < 2; w++) {
        int qrow = qt * 128 + wave * 32 + w * 16 + l16;
        const short* qptr = Qb + ((size_t)bhh * Sn + qrow) * DKn + quad * 8;
        qf[w][0] = *(const fragb*)(qptr);
        qf[w][1] = *(const fragb*)(qptr + 32);
    }

    f4 ctx[2][4];
    #pragma unroll
    for (int w = 0; w < 2; w++)
        #pragma unroll
        for (int dt = 0; dt < 4; dt++) {
            ctx[w][dt][0] = 0.f; ctx[w][dt][1] = 0.f;
            ctx[w][dt][2] = 0.f; ctx[w][dt][3] = 0.f;
        }
    f4 lacc[2];
    lacc[0][0] = 0.f; lacc[0][1] = 0.f; lacc[0][2] = 0.f; lacc[0][3] = 0.f;
    lacc[1] = lacc[0];

    const int lr = lane >> 3;
    const int sc = ((lane & 7) ^ lr) * 8;
    const short* Kg = Kb  + (size_t)bhh * Sn * DKn;
    const short* Vg = Vtb + (size_t)bhh * DKn * Sn;
    const short* mg = mfb + (size_t)b * Sn;

    const short* Ksrc = Kg + (size_t)(wave * 16 + lr) * DKn + sc;
    const short* Vsrc = Vg + (size_t)(wave * 16 + lr) * Sn + sc;

    const int c0 = ((quad ^ (l16 & 7)) * 8);

    const int kt0 = split * 16;
    for (int kt = kt0; kt < kt0 + 16; kt++) {
        __syncthreads();
        GLOAD(Ksrc + (size_t)kt * 4096,             &Ks[(wave * 16) * 64]);
        GLOAD(Ksrc + (size_t)kt * 4096 + 8 * DKn,   &Ks[(wave * 16 + 8) * 64]);
        GLOAD(Vsrc + (size_t)kt * 64,               &Vs[(wave * 16) * 64]);
        GLOAD(Vsrc + (size_t)kt * 64 + 8 * Sn,      &Vs[(wave * 16 + 8) * 64]);
        if (tid < 8)
            *(uint4*)&mfs[tid * 8] = *(const uint4*)(mg + kt * 64 + tid * 8);
        __syncthreads();

        #pragma unroll
        for (int t = 0; t < 4; t++) {
            fragb k0 = *(const fragb*)&Ks[(t * 16 + l16) * 64 + c0];
            fragb k1 = *(const fragb*)&Ks[(t * 16 + l16) * 64 + (c0 ^ 32)];
            #pragma unroll
            for (int w = 0; w < 2; w++) {
                f4 a; a[0] = 0.f; a[1] = 0.f; a[2] = 0.f; a[3] = 0.f;
                a = __builtin_amdgcn_mfma_f32_16x16x32_bf16(k0, qf[w][0], a, 0, 0, 0);
                a = __builtin_amdgcn_mfma_f32_16x16x32_bf16(k1, qf[w][1], a, 0, 0, 0);
                // raw v_exp_f32 (log2e folded into Q): 1 instr vs OCML's ~8
                unsigned u0 = __float_as_uint(__builtin_amdgcn_exp2f(a[0]));
                unsigned u1 = __float_as_uint(__builtin_amdgcn_exp2f(a[1]));
                unsigned u2 = __float_as_uint(__builtin_amdgcn_exp2f(a[2]));
                unsigned u3 = __float_as_uint(__builtin_amdgcn_exp2f(a[3]));
                uint2 pw;
                pw.x = __builtin_amdgcn_perm(u1, u0, 0x07060302u);
                pw.y = __builtin_amdgcn_perm(u3, u2, 0x07060302u);
                *(uint2*)&Ps[wave][(w * 16 + l16) * LP + 16 * t + quad * 4] = pw;
            }
        }

        fragb p[2][2];
        #pragma unroll
        for (int w = 0; w < 2; w++) {
            p[w][0] = *(const fragb*)&Ps[wave][(w * 16 + l16) * LP + quad * 8];
            p[w][1] = *(const fragb*)&Ps[wave][(w * 16 + l16) * LP + quad * 8 + 32];
        }
        fragb m0 = *(const fragb*)&mfs[quad * 8];
        fragb m1 = *(const fragb*)&mfs[quad * 8 + 32];
        #pragma unroll
        for (int w = 0; w < 2; w++) {
            lacc[w] = __builtin_amdgcn_mfma_f32_16x16x32_bf16(p[w][0], m0, lacc[w], 0, 0, 0);
            lacc[w] = __builtin_amdgcn_mfma_f32_16x16x32_bf16(p[w][1], m1, lacc[w], 0, 0, 0);
        }
        #pragma unroll
        for (int dt = 0; dt < 4; dt++) {
            fragb v0 = *(const fragb*)&Vs[(dt * 16 + l16) * 64 + c0];
            fragb v1 = *(const fragb*)&Vs[(dt * 16 + l16) * 64 + (c0 ^ 32)];
            #pragma unroll
            for (int w = 0; w < 2; w++) {
                ctx[w][dt] = __builtin_amdgcn_mfma_f32_16x16x32_bf16(p[w][0], v0, ctx[w][dt], 0, 0, 0);
                ctx[w][dt] = __builtin_amdgcn_mfma_f32_16x16x32_bf16(p[w][1], v1, ctx[w][dt], 0, 0, 0);
            }
        }
    }

    float* cp  = split ? ctxp1 : ctxp0;
    float* lpp = lp + (size_t)split * BHS;
    #pragma unroll
    for (int w = 0; w < 2; w++)
        #pragma unroll
        for (int r = 0; r < 4; r++) {
            int row = qt * 128 + wave * 32 + w * 16 + quad * 4 + r;
            if (l16 == 0) lpp[(size_t)bhh * Sn + row] = lacc[w][r];
            #pragma unroll
            for (int dt = 0; dt < 4; dt++)
                cp[((size_t)(b * Sn + row)) * Dn + h * DKn + dt * 16 + l16] =
                    ctx[w][dt][r];
        }
}

// ---------------- reduce: merge split partials, normalize, emit fp16 --------
__global__ __launch_bounds__(256) void reduce_ctx(
    const float* __restrict__ c0, const float* __restrict__ c1,
    const float* __restrict__ lp, short* __restrict__ Ch)
{
    int i4 = blockIdx.x * 256 + threadIdx.x;
    int e    = i4 << 2;
    int brow = e >> 10;
    int d    = e & 1023;
    int b    = brow >> 11;
    int row  = brow & (Sn - 1);
    int h    = d >> 6;
    size_t li = (size_t)(b * Hn + h) * Sn + row;
    float l = lp[li] + lp[BHS + li];
    float inv = 1.f / l;
    float4 v0 = ((const float4*)c0)[i4];
    float4 v1 = ((const float4*)c1)[i4];
    ushort4 o;
    o.x = f2h((v0.x + v1.x) * inv);
    o.y = f2h((v0.y + v1.y) * inv);
    o.z = f2h((v0.z + v1.z) * inv);
    o.w = f2h((v0.w + v1.w) * inv);
    ((ushort4*)Ch)[i4] = o;
}

// ---------------- launch ----------------
extern "C" void kernel_launch(void* const* d_in, const int* in_sizes, int n_in,
                              void* d_out, int out_size, void* d_ws, size_t ws_size,
                              hipStream_t stream) {
    const float* x    = (const float*)d_in[0];
    const int*   mask = (const int*)d_in[1];
    const float* Wq   = (const float*)d_in[2];
    const float* bq   = (const float*)d_in[3];
    const float* Wk   = (const float*)d_in[4];
    const float* bk   = (const float*)d_in[5];
    const float* Wv   = (const float*)d_in[6];
    const float* bv   = (const float*)d_in[7];
    const float* Wo   = (const float*)d_in[8];
    const float* bo   = (const float*)d_in[9];
    float* out = (float*)d_out;

    char* ws = (char*)d_ws;
    const size_t MB = 1024u * 1024u;
    short* xh    = (short*)(ws + 0 * MB);    // 8 MB fp16 (dead after QKV)
    short* Wqh   = (short*)(ws + 8 * MB);
    short* Wkh   = (short*)(ws + 10 * MB);
    short* Wvh   = (short*)(ws + 12 * MB);
    short* Qb    = (short*)(ws + 16 * MB);
    short* Kb    = (short*)(ws + 24 * MB);
    short* Vtb   = (short*)(ws + 32 * MB);
    float* ctxp0 = (float*)(ws + 0 * MB);    // overlays dead region
    float* ctxp1 = (float*)(ws + 40 * MB);
    short* Woh   = (short*)(ws + 56 * MB);
    float* lp    = (float*)(ws + 58 * MB);
    short* mfb   = (short*)(ws + 59 * MB);
    short* Ch    = (short*)(ws + 60 * MB);

    const int PRE = NF4 + (Bn * Sn) / 4;
    prep<<<(PRE + 255) / 256, 256, 0, stream>>>(
        x, Wq, Wk, Wv, Wo, mask, xh, Wqh, Wkh, Wvh, Woh, mfb);

    gemm_qkv<<<dim3(24, 32), 256, 0, stream>>>(
        xh, Wqh, bq, Wkh, bk, Wvh, bv, mask, Qb, Kb, Vtb);

    attn_mfma<<<dim3(Bn * Hn * (Sn / 128) * 2), 256, 0, stream>>>(
        Qb, Kb, Vtb, mfb, ctxp0, ctxp1, lp);

    reduce_ctx<<<dim3(NX / 4 / 256), 256, 0, stream>>>(ctxp0, ctxp1, lp, Ch);

    gemm_out<<<dim3(8, 32), 256, 0, stream>>>(Ch, Woh, bo, out);
}

// Round 3
// 229.294 us; speedup vs baseline: 1.0270x; 1.0021x over previous
//
#include <hip/hip_runtime.h>
#include <hip/hip_bf16.h>
#include <math.h>

// Problem constants
#define Bn 2
#define Sn 2048
#define Dn 1024
#define Hn 16
#define DKn 64
#define BHS (Bn * Hn * Sn)

using fragb  = __attribute__((ext_vector_type(8))) short;      // 8 bf16
using frag16 = __attribute__((ext_vector_type(8))) _Float16;   // 8 fp16
using f4     = __attribute__((ext_vector_type(4))) float;

__device__ __forceinline__ short f2bf(float f) {
    union { float f; unsigned u; } v; v.f = f;
    unsigned r = v.u + 0x7FFF + ((v.u >> 16) & 1);   // RNE
    return (short)(r >> 16);
}
__device__ __forceinline__ unsigned short f2h(float f) {
    _Float16 h = (_Float16)f;                         // RNE
    unsigned short s; __builtin_memcpy(&s, &h, 2); return s;
}

// async global->LDS, 16B per lane; LDS dest = wave-uniform base + lane*16
#define GLOAD(gptr, lptr)                                                     \
    __builtin_amdgcn_global_load_lds(                                         \
        (const __attribute__((address_space(1))) unsigned int*)(const void*)(gptr), \
        (__attribute__((address_space(3))) unsigned int*)(void*)(lptr), 16, 0, 0)

// ---------------- prep: fp32 -> fp16 casts (x4 vectorized) + bf16 mask row --
#define NX (Bn * Sn * Dn)      // 4M
#define NW (Dn * Dn)           // 1M
#define NF4 ((NX + 4 * NW) / 4)

__global__ __launch_bounds__(256) void prep(
    const float* __restrict__ x,  const float* __restrict__ Wq,
    const float* __restrict__ Wk, const float* __restrict__ Wv,
    const float* __restrict__ Wo, const int* __restrict__ mask,
    short* __restrict__ xh,
    short* __restrict__ Wqh, short* __restrict__ Wkh,
    short* __restrict__ Wvh, short* __restrict__ Woh,
    short* __restrict__ mfb)
{
    int i = blockIdx.x * 256 + threadIdx.x;
    if (i < NF4) {
        int e = i << 2;
        const float* src; short* dst; int j;
        if (e < NX)               { src = x;  dst = xh;  j = e; }
        else if (e < NX + NW)     { src = Wq; dst = Wqh; j = e - NX; }
        else if (e < NX + 2 * NW) { src = Wk; dst = Wkh; j = e - NX - NW; }
        else if (e < NX + 3 * NW) { src = Wv; dst = Wvh; j = e - NX - 2 * NW; }
        else                      { src = Wo; dst = Woh; j = e - NX - 3 * NW; }
        float4 v = *(const float4*)(src + j);
        ushort4 o;
        o.x = f2h(v.x); o.y = f2h(v.y); o.z = f2h(v.z); o.w = f2h(v.w);
        *(ushort4*)(dst + j) = o;
    } else {
        int j = (i - NF4) << 2;
        if (j < Bn * Sn) {
            int4 m = *(const int4*)(mask + j);
            ushort4 o;
            o.x = m.x ? 0x3F80 : 0; o.y = m.y ? 0x3F80 : 0;
            o.z = m.z ? 0x3F80 : 0; o.w = m.w ? 0x3F80 : 0;
            *(ushort4*)(mfb + j) = o;
        }
    }
}

// ---- GEMM machinery: 128-wide tiles, BK=32, compile-time double buffer -----
// Swizzle (both sides, same involution): LDS phys (row, c) holds logical
// chunk c ^ ((row>>1)&3).  Staged via pre-swizzled GLOBAL source address
// (global_load_lds dest stays linear); fragment reads apply the same XOR.
// 8-way ds_read_b128 bank conflict -> 2-way (free).
// Schedule per K-pair (T3 minimum 2-phase, static buffers so the compiler
// does NOT force vmcnt(0) before the unrelated buffer's ds_reads):
//   STAGE(other, k+32); COMPUTE(cur); __syncthreads();  (one drain per tile)

// ---------------- QKV GEMM: fp16, 128x128, dbuf, XCD swizzle ----------------
__global__ __launch_bounds__(256) void gemm_qkv(
    const short* __restrict__ A,
    const short* __restrict__ W0, const float* __restrict__ b0,
    const short* __restrict__ W1, const float* __restrict__ b1,
    const short* __restrict__ W2, const float* __restrict__ b2,
    const int* __restrict__ mask,
    short* __restrict__ Qb, short* __restrict__ Kb, short* __restrict__ Vtb)
{
    __shared__ __align__(16) short As0[128 * 32];
    __shared__ __align__(16) short Bs0[128 * 32];
    __shared__ __align__(16) short As1[128 * 32];
    __shared__ __align__(16) short Bs1[128 * 32];

    const int tid  = threadIdx.x;
    const int wave = tid >> 6;
    const int lane = tid & 63;
    const int quad = lane >> 4;
    const int l16  = lane & 15;
    const int wm   = wave >> 1;
    const int wn   = wave & 1;

    // XCD-aware swizzle: 768 blocks, 8 XCDs, 96 blocks/XCD (bijective: 768%8==0).
    // XCD k owns by in [4k,4k+4): its 4 x-panels (1 MB) stay L2-resident.
    const int orig = blockIdx.y * 24 + blockIdx.x;
    const int swz  = (orig & 7) * 96 + (orig >> 3);
    const int by   = swz / 24;
    const int bx   = swz - by * 24;
    const int m0   = by * 128;
    const int n0   = bx * 128;
    const int widx = n0 >> 10;
    const int nl0  = n0 & 1023;

    const short* Wp   = widx == 0 ? W0 : (widx == 1 ? W1 : W2);
    const float* bias = widx == 0 ? b0 : (widx == 1 ? b1 : b2);

    f4 acc[4][4];
    #pragma unroll
    for (int i = 0; i < 4; i++)
        #pragma unroll
        for (int j = 0; j < 4; j++) {
            acc[i][j][0] = 0.f; acc[i][j][1] = 0.f;
            acc[i][j][2] = 0.f; acc[i][j][3] = 0.f;
        }

    const int K  = Dn;
    const int r0 = tid >> 2;                              // staged row 0..63
    const int sc = ((tid & 3) ^ ((tid >> 3) & 3)) * 8;    // pre-swizzled chunk
    const short* Ar0 = A  + (size_t)(m0  + r0)      * K + sc;
    const short* Ar1 = A  + (size_t)(m0  + r0 + 64) * K + sc;
    const short* Br0 = Wp + (size_t)(nl0 + r0)      * K + sc;
    const short* Br1 = Wp + (size_t)(nl0 + r0 + 64) * K + sc;

    const int cA = (quad ^ ((l16 >> 1) & 3)) * 8;         // swizzled read chunk

#define STAGEQ(AS, BS, kk) do {                                               \
    GLOAD(Ar0 + (kk), &AS[wave * 512]);                                       \
    GLOAD(Ar1 + (kk), &AS[2048 + wave * 512]);                                \
    GLOAD(Br0 + (kk), &BS[wave * 512]);                                       \
    GLOAD(Br1 + (kk), &BS[2048 + wave * 512]);                                \
} while (0)

#define COMPUTEQ(AS, BS) do {                                                 \
    frag16 a_[4], b_[4];                                                      \
    _Pragma("unroll")                                                         \
    for (int mi = 0; mi < 4; mi++)                                            \
        a_[mi] = *(const frag16*)&AS[(wm * 64 + mi * 16 + l16) * 32 + cA];    \
    _Pragma("unroll")                                                         \
    for (int ni = 0; ni < 4; ni++)                                            \
        b_[ni] = *(const frag16*)&BS[(wn * 64 + ni * 16 + l16) * 32 + cA];    \
    _Pragma("unroll")                                                         \
    for (int mi = 0; mi < 4; mi++)                                            \
        _Pragma("unroll")                                                     \
        for (int ni = 0; ni < 4; ni++)                                        \
            acc[mi][ni] = __builtin_amdgcn_mfma_f32_16x16x32_f16(             \
                a_[mi], b_[ni], acc[mi][ni], 0, 0, 0);                        \
} while (0)

    STAGEQ(As0, Bs0, 0);
    __syncthreads();
    for (int k0 = 0; k0 < K - 64; k0 += 64) {
        STAGEQ(As1, Bs1, k0 + 32);       // prefetch next tile (other buffer)
        COMPUTEQ(As0, Bs0);              // overlap with its latency
        __syncthreads();                 // one drain per tile
        STAGEQ(As0, Bs0, k0 + 64);
        COMPUTEQ(As1, Bs1);
        __syncthreads();
    }
    STAGEQ(As1, Bs1, K - 32);
    COMPUTEQ(As0, Bs0);
    __syncthreads();
    COMPUTEQ(As1, Bs1);

    const float QSCALE = 0.125f * 1.44269504088896340736f;

    #pragma unroll
    for (int mi = 0; mi < 4; mi++) {
        #pragma unroll
        for (int ni = 0; ni < 4; ni++) {
            int nl = nl0 + wn * 64 + ni * 16 + l16;
            float bv = bias[nl];
            #pragma unroll
            for (int r = 0; r < 4; r++) {
                int m = m0 + wm * 64 + mi * 16 + quad * 4 + r;
                float v = acc[mi][ni][r] + bv;
                int b  = m >> 11, s = m & (Sn - 1);
                int h  = nl >> 6, dk = nl & 63;
                if (widx == 0)
                    Qb[((size_t)(b * Hn + h) * Sn + s) * DKn + dk] = f2bf(v * QSCALE);
                else if (widx == 1)
                    Kb[((size_t)(b * Hn + h) * Sn + s) * DKn + dk] = f2bf(v);
                else {
                    float mv = (float)mask[b * Sn + s];
                    Vtb[((size_t)(b * Hn + h) * DKn + dk) * Sn + s] = f2bf(v * mv);
                }
            }
        }
    }
}

// ---------------- Out GEMM: fp16, 64x128, dbuf, XCD swizzle, fp32 out -------
__global__ __launch_bounds__(256) void gemm_out(
    const short* __restrict__ A, const short* __restrict__ Wp,
    const float* __restrict__ bias, float* __restrict__ outf)
{
    __shared__ __align__(16) short As0[64 * 32];
    __shared__ __align__(16) short Bs0[128 * 32];
    __shared__ __align__(16) short As1[64 * 32];
    __shared__ __align__(16) short Bs1[128 * 32];

    const int tid  = threadIdx.x;
    const int wave = tid >> 6;
    const int lane = tid & 63;
    const int quad = lane >> 4;
    const int l16  = lane & 15;
    const int wm   = wave >> 1;
    const int wn   = wave & 1;

    // XCD swizzle: 512 blocks, 64/XCD (bijective: 512%8==0)
    const int orig = blockIdx.y * 8 + blockIdx.x;
    const int swz  = (orig & 7) * 64 + (orig >> 3);
    const int m0   = (swz >> 3) * 64;
    const int n0   = (swz & 7) * 128;

    f4 acc[2][4];
    #pragma unroll
    for (int i = 0; i < 2; i++)
        #pragma unroll
        for (int j = 0; j < 4; j++) {
            acc[i][j][0] = 0.f; acc[i][j][1] = 0.f;
            acc[i][j][2] = 0.f; acc[i][j][3] = 0.f;
        }

    const int K  = Dn;
    const int r0 = tid >> 2;
    const int sc = ((tid & 3) ^ ((tid >> 3) & 3)) * 8;
    const short* Ao0 = A  + (size_t)(m0 + r0)      * K + sc;
    const short* Bo0 = Wp + (size_t)(n0 + r0)      * K + sc;
    const short* Bo1 = Wp + (size_t)(n0 + r0 + 64) * K + sc;

    const int cA = (quad ^ ((l16 >> 1) & 3)) * 8;

#define STAGEO(AS, BS, kk) do {                                               \
    GLOAD(Ao0 + (kk), &AS[wave * 512]);                                       \
    GLOAD(Bo0 + (kk), &BS[wave * 512]);                                       \
    GLOAD(Bo1 + (kk), &BS[2048 + wave * 512]);                                \
} while (0)

#define COMPUTEO(AS, BS) do {                                                 \
    frag16 a_[2], b_[4];                                                      \
    _Pragma("unroll")                                                         \
    for (int mi = 0; mi < 2; mi++)                                            \
        a_[mi] = *(const frag16*)&AS[(wm * 32 + mi * 16 + l16) * 32 + cA];    \
    _Pragma("unroll")                                                         \
    for (int ni = 0; ni < 4; ni++)                                            \
        b_[ni] = *(const frag16*)&BS[(wn * 64 + ni * 16 + l16) * 32 + cA];    \
    _Pragma("unroll")                                                         \
    for (int mi = 0; mi < 2; mi++)                                            \
        _Pragma("unroll")                                                     \
        for (int ni = 0; ni < 4; ni++)                                        \
            acc[mi][ni] = __builtin_amdgcn_mfma_f32_16x16x32_f16(             \
                a_[mi], b_[ni], acc[mi][ni], 0, 0, 0);                        \
} while (0)

    STAGEO(As0, Bs0, 0);
    __syncthreads();
    for (int k0 = 0; k0 < K - 64; k0 += 64) {
        STAGEO(As1, Bs1, k0 + 32);
        COMPUTEO(As0, Bs0);
        __syncthreads();
        STAGEO(As0, Bs0, k0 + 64);
        COMPUTEO(As1, Bs1);
        __syncthreads();
    }
    STAGEO(As1, Bs1, K - 32);
    COMPUTEO(As0, Bs0);
    __syncthreads();
    COMPUTEO(As1, Bs1);

    #pragma unroll
    for (int mi = 0; mi < 2; mi++) {
        #pragma unroll
        for (int ni = 0; ni < 4; ni++) {
            int nl = n0 + wn * 64 + ni * 16 + l16;
            float bv = bias[nl];
            #pragma unroll
            for (int r = 0; r < 4; r++) {
                int m = m0 + wm * 32 + mi * 16 + quad * 4 + r;
                outf[(size_t)m * Dn + nl] = acc[mi][ni][r] + bv;
            }
        }
    }
}

// ---------------- Flash attention: split-K x2, raw v_exp_f32 softmax --------
#define LP  72

__global__ __launch_bounds__(256) void attn_mfma(
    const short* __restrict__ Qb, const short* __restrict__ Kb,
    const short* __restrict__ Vtb, const short* __restrict__ mfb,
    float* __restrict__ ctxp0, float* __restrict__ ctxp1,
    float* __restrict__ lp)
{
    __shared__ __align__(16) short Ks[64 * 64];
    __shared__ __align__(16) short Vs[64 * 64];
    __shared__ short Ps[4][32 * LP];
    __shared__ __align__(16) short mfs[64];

    const int tid  = threadIdx.x;
    const int wave = tid >> 6;
    const int lane = tid & 63;
    const int quad = lane >> 4;
    const int l16  = lane & 15;

    const int split = blockIdx.x & 1;
    const int rest  = blockIdx.x >> 1;
    const int qt  = rest & 15;
    const int bhh = rest >> 4;
    const int b   = bhh >> 4;
    const int h   = bhh & 15;

    fragb qf[2][2];
    #pragma unroll
    for (int w = 0; w < 2; w++) {
        int qrow = qt * 128 + wave * 32 + w * 16 + l16;
        const short* qptr = Qb + ((size_t)bhh * Sn + qrow) * DKn + quad * 8;
        qf[w][0] = *(const fragb*)(qptr);
        qf[w][1] = *(const fragb*)(qptr + 32);
    }

    f4 ctx[2][4];
    #pragma unroll
    for (int w = 0; w < 2; w++)
        #pragma unroll
        for (int dt = 0; dt < 4; dt++) {
            ctx[w][dt][0] = 0.f; ctx[w][dt][1] = 0.f;
            ctx[w][dt][2] = 0.f; ctx[w][dt][3] = 0.f;
        }
    f4 lacc[2];
    lacc[0][0] = 0.f; lacc[0][1] = 0.f; lacc[0][2] = 0.f; lacc[0][3] = 0.f;
    lacc[1] = lacc[0];

    const int lr = lane >> 3;
    const int sc = ((lane & 7) ^ lr) * 8;
    const short* Kg = Kb  + (size_t)bhh * Sn * DKn;
    const short* Vg = Vtb + (size_t)bhh * DKn * Sn;
    const short* mg = mfb + (size_t)b * Sn;

    const short* Ksrc = Kg + (size_t)(wave * 16 + lr) * DKn + sc;
    const short* Vsrc = Vg + (size_t)(wave * 16 + lr) * Sn + sc;

    const int c0 = ((quad ^ (l16 & 7)) * 8);

    const int kt0 = split * 16;
    for (int kt = kt0; kt < kt0 + 16; kt++) {
        __syncthreads();
        GLOAD(Ksrc + (size_t)kt * 4096,             &Ks[(wave * 16) * 64]);
        GLOAD(Ksrc + (size_t)kt * 4096 + 8 * DKn,   &Ks[(wave * 16 + 8) * 64]);
        GLOAD(Vsrc + (size_t)kt * 64,               &Vs[(wave * 16) * 64]);
        GLOAD(Vsrc + (size_t)kt * 64 + 8 * Sn,      &Vs[(wave * 16 + 8) * 64]);
        if (tid < 8)
            *(uint4*)&mfs[tid * 8] = *(const uint4*)(mg + kt * 64 + tid * 8);
        __syncthreads();

        #pragma unroll
        for (int t = 0; t < 4; t++) {
            fragb k0 = *(const fragb*)&Ks[(t * 16 + l16) * 64 + c0];
            fragb k1 = *(const fragb*)&Ks[(t * 16 + l16) * 64 + (c0 ^ 32)];
            #pragma unroll
            for (int w = 0; w < 2; w++) {
                f4 a; a[0] = 0.f; a[1] = 0.f; a[2] = 0.f; a[3] = 0.f;
                a = __builtin_amdgcn_mfma_f32_16x16x32_bf16(k0, qf[w][0], a, 0, 0, 0);
                a = __builtin_amdgcn_mfma_f32_16x16x32_bf16(k1, qf[w][1], a, 0, 0, 0);
                // raw v_exp_f32 (log2e folded into Q): 1 instr vs OCML's ~8
                unsigned u0 = __float_as_uint(__builtin_amdgcn_exp2f(a[0]));
                unsigned u1 = __float_as_uint(__builtin_amdgcn_exp2f(a[1]));
                unsigned u2 = __float_as_uint(__builtin_amdgcn_exp2f(a[2]));
                unsigned u3 = __float_as_uint(__builtin_amdgcn_exp2f(a[3]));
                uint2 pw;
                pw.x = __builtin_amdgcn_perm(u1, u0, 0x07060302u);
                pw.y = __builtin_amdgcn_perm(u3, u2, 0x07060302u);
                *(uint2*)&Ps[wave][(w * 16 + l16) * LP + 16 * t + quad * 4] = pw;
            }
        }

        fragb p[2][2];
        #pragma unroll
        for (int w = 0; w < 2; w++) {
            p[w][0] = *(const fragb*)&Ps[wave][(w * 16 + l16) * LP + quad * 8];
            p[w][1] = *(const fragb*)&Ps[wave][(w * 16 + l16) * LP + quad * 8 + 32];
        }
        fragb m0 = *(const fragb*)&mfs[quad * 8];
        fragb m1 = *(const fragb*)&mfs[quad * 8 + 32];
        #pragma unroll
        for (int w = 0; w < 2; w++) {
            lacc[w] = __builtin_amdgcn_mfma_f32_16x16x32_bf16(p[w][0], m0, lacc[w], 0, 0, 0);
            lacc[w] = __builtin_amdgcn_mfma_f32_16x16x32_bf16(p[w][1], m1, lacc[w], 0, 0, 0);
        }
        #pragma unroll
        for (int dt = 0; dt < 4; dt++) {
            fragb v0 = *(const fragb*)&Vs[(dt * 16 + l16) * 64 + c0];
            fragb v1 = *(const fragb*)&Vs[(dt * 16 + l16) * 64 + (c0 ^ 32)];
            #pragma unroll
            for (int w = 0; w < 2; w++) {
                ctx[w][dt] = __builtin_amdgcn_mfma_f32_16x16x32_bf16(p[w][0], v0, ctx[w][dt], 0, 0, 0);
                ctx[w][dt] = __builtin_amdgcn_mfma_f32_16x16x32_bf16(p[w][1], v1, ctx[w][dt], 0, 0, 0);
            }
        }
    }

    float* cp  = split ? ctxp1 : ctxp0;
    float* lpp = lp + (size_t)split * BHS;
    #pragma unroll
    for (int w = 0; w < 2; w++)
        #pragma unroll
        for (int r = 0; r < 4; r++) {
            int row = qt * 128 + wave * 32 + w * 16 + quad * 4 + r;
            if (l16 == 0) lpp[(size_t)bhh * Sn + row] = lacc[w][r];
            #pragma unroll
            for (int dt = 0; dt < 4; dt++)
                cp[((size_t)(b * Sn + row)) * Dn + h * DKn + dt * 16 + l16] =
                    ctx[w][dt][r];
        }
}

// ---------------- reduce: merge split partials, normalize, emit fp16 --------
__global__ __launch_bounds__(256) void reduce_ctx(
    const float* __restrict__ c0, const float* __restrict__ c1,
    const float* __restrict__ lp, short* __restrict__ Ch)
{
    int i4 = blockIdx.x * 256 + threadIdx.x;
    int e    = i4 << 2;
    int brow = e >> 10;
    int d    = e & 1023;
    int b    = brow >> 11;
    int row  = brow & (Sn - 1);
    int h    = d >> 6;
    size_t li = (size_t)(b * Hn + h) * Sn + row;
    float l = lp[li] + lp[BHS + li];
    float inv = 1.f / l;
    float4 v0 = ((const float4*)c0)[i4];
    float4 v1 = ((const float4*)c1)[i4];
    ushort4 o;
    o.x = f2h((v0.x + v1.x) * inv);
    o.y = f2h((v0.y + v1.y) * inv);
    o.z = f2h((v0.z + v1.z) * inv);
    o.w = f2h((v0.w + v1.w) * inv);
    ((ushort4*)Ch)[i4] = o;
}

// ---------------- launch ----------------
extern "C" void kernel_launch(void* const* d_in, const int* in_sizes, int n_in,
                              void* d_out, int out_size, void* d_ws, size_t ws_size,
                              hipStream_t stream) {
    const float* x    = (const float*)d_in[0];
    const int*   mask = (const int*)d_in[1];
    const float* Wq   = (const float*)d_in[2];
    const float* bq   = (const float*)d_in[3];
    const float* Wk   = (const float*)d_in[4];
    const float* bk   = (const float*)d_in[5];
    const float* Wv   = (const float*)d_in[6];
    const float* bv   = (const float*)d_in[7];
    const float* Wo   = (const float*)d_in[8];
    const float* bo   = (const float*)d_in[9];
    float* out = (float*)d_out;

    char* ws = (char*)d_ws;
    const size_t MB = 1024u * 1024u;
    short* xh    = (short*)(ws + 0 * MB);    // 8 MB fp16 (dead after QKV)
    short* Wqh   = (short*)(ws + 8 * MB);
    short* Wkh   = (short*)(ws + 10 * MB);
    short* Wvh   = (short*)(ws + 12 * MB);
    short* Qb    = (short*)(ws + 16 * MB);
    short* Kb    = (short*)(ws + 24 * MB);
    short* Vtb   = (short*)(ws + 32 * MB);
    float* ctxp0 = (float*)(ws + 0 * MB);    // overlays dead region
    float* ctxp1 = (float*)(ws + 40 * MB);
    short* Woh   = (short*)(ws + 56 * MB);
    float* lp    = (float*)(ws + 58 * MB);
    short* mfb   = (short*)(ws + 59 * MB);
    short* Ch    = (short*)(ws + 60 * MB);

    const int PRE = NF4 + (Bn * Sn) / 4;
    prep<<<(PRE + 255) / 256, 256, 0, stream>>>(
        x, Wq, Wk, Wv, Wo, mask, xh, Wqh, Wkh, Wvh, Woh, mfb);

    gemm_qkv<<<dim3(24, 32), 256, 0, stream>>>(
        xh, Wqh, bq, Wkh, bk, Wvh, bv, mask, Qb, Kb, Vtb);

    attn_mfma<<<dim3(Bn * Hn * (Sn / 128) * 2), 256, 0, stream>>>(
        Qb, Kb, Vtb, mfb, ctxp0, ctxp1, lp);

    reduce_ctx<<<dim3(NX / 4 / 256), 256, 0, stream>>>(ctxp0, ctxp1, lp, Ch);

    gemm_out<<<dim3(8, 64), 256, 0, stream>>>(Ch, Woh, bo, out);
}

// Round 4
// 223.687 us; speedup vs baseline: 1.0528x; 1.0251x over previous
//
#include <hip/hip_runtime.h>
#include <hip/hip_bf16.h>
#include <math.h>

// Problem constants
#define Bn 2
#define Sn 2048
#define Dn 1024
#define Hn 16
#define DKn 64
#define BHS (Bn * Hn * Sn)

using fragb  = __attribute__((ext_vector_type(8))) short;      // 8 bf16
using frag16 = __attribute__((ext_vector_type(8))) _Float16;   // 8 fp16
using f4     = __attribute__((ext_vector_type(4))) float;

__device__ __forceinline__ short f2bf(float f) {
    union { float f; unsigned u; } v; v.f = f;
    unsigned r = v.u + 0x7FFF + ((v.u >> 16) & 1);   // RNE
    return (short)(r >> 16);
}
__device__ __forceinline__ unsigned short f2h(float f) {
    _Float16 h = (_Float16)f;                         // RNE
    unsigned short s; __builtin_memcpy(&s, &h, 2); return s;
}

// async global->LDS, 16B per lane; LDS dest = wave-uniform base + lane*16
#define GLOAD(gptr, lptr)                                                     \
    __builtin_amdgcn_global_load_lds(                                         \
        (const __attribute__((address_space(1))) unsigned int*)(const void*)(gptr), \
        (__attribute__((address_space(3))) unsigned int*)(void*)(lptr), 16, 0, 0)

// ---------------- prep: fp32 -> fp16 casts (x4 vectorized) + bf16 mask row --
#define NX (Bn * Sn * Dn)      // 4M
#define NW (Dn * Dn)           // 1M
#define NF4 ((NX + 4 * NW) / 4)

__global__ __launch_bounds__(256) void prep(
    const float* __restrict__ x,  const float* __restrict__ Wq,
    const float* __restrict__ Wk, const float* __restrict__ Wv,
    const float* __restrict__ Wo, const int* __restrict__ mask,
    short* __restrict__ xh,
    short* __restrict__ Wqh, short* __restrict__ Wkh,
    short* __restrict__ Wvh, short* __restrict__ Woh,
    short* __restrict__ mfb)
{
    int i = blockIdx.x * 256 + threadIdx.x;
    if (i < NF4) {
        int e = i << 2;
        const float* src; short* dst; int j;
        if (e < NX)               { src = x;  dst = xh;  j = e; }
        else if (e < NX + NW)     { src = Wq; dst = Wqh; j = e - NX; }
        else if (e < NX + 2 * NW) { src = Wk; dst = Wkh; j = e - NX - NW; }
        else if (e < NX + 3 * NW) { src = Wv; dst = Wvh; j = e - NX - 2 * NW; }
        else                      { src = Wo; dst = Woh; j = e - NX - 3 * NW; }
        float4 v = *(const float4*)(src + j);
        ushort4 o;
        o.x = f2h(v.x); o.y = f2h(v.y); o.z = f2h(v.z); o.w = f2h(v.w);
        *(ushort4*)(dst + j) = o;
    } else {
        int j = (i - NF4) << 2;
        if (j < Bn * Sn) {
            int4 m = *(const int4*)(mask + j);
            ushort4 o;
            o.x = m.x ? 0x3F80 : 0; o.y = m.y ? 0x3F80 : 0;
            o.z = m.z ? 0x3F80 : 0; o.w = m.w ? 0x3F80 : 0;
            *(ushort4*)(mfb + j) = o;
        }
    }
}

// ---- GEMM machinery: R0 per-block structure (BK=32, single buffer, two
// barriers per K-step), but SMALL tiles so the grid supplies 4-6 co-resident
// blocks/CU (occupancy was grid-limited at 768 blocks: 24% = ~2 blocks/CU).
// Cross-block TLP is what hides the staging latency at this structure.
// LDS swizzle (both sides, same involution, verified R1-R3): phys chunk c
// holds logical chunk c ^ ((row>>1)&3); staged via pre-swizzled GLOBAL source
// (linear global_load_lds dest), read with the same XOR. Conflicts: 0.

// ---------------- QKV GEMM: fp16, 64x128 tile, 1536 blocks ------------------
__global__ __launch_bounds__(256) void gemm_qkv(
    const short* __restrict__ A,
    const short* __restrict__ W0, const float* __restrict__ b0,
    const short* __restrict__ W1, const float* __restrict__ b1,
    const short* __restrict__ W2, const float* __restrict__ b2,
    const int* __restrict__ mask,
    short* __restrict__ Qb, short* __restrict__ Kb, short* __restrict__ Vtb)
{
    __shared__ __align__(16) short As[64 * 32];     // 4 KB
    __shared__ __align__(16) short Bs[128 * 32];    // 8 KB

    const int tid  = threadIdx.x;
    const int wave = tid >> 6;
    const int lane = tid & 63;
    const int quad = lane >> 4;
    const int l16  = lane & 15;
    const int wm   = wave >> 1;
    const int wn   = wave & 1;

    const int m0   = blockIdx.y * 64;
    const int n0   = blockIdx.x * 128;
    const int widx = n0 >> 10;
    const int nl0  = n0 & 1023;

    const short* Wp   = widx == 0 ? W0 : (widx == 1 ? W1 : W2);
    const float* bias = widx == 0 ? b0 : (widx == 1 ? b1 : b2);

    f4 acc[2][4];
    #pragma unroll
    for (int i = 0; i < 2; i++)
        #pragma unroll
        for (int j = 0; j < 4; j++) {
            acc[i][j][0] = 0.f; acc[i][j][1] = 0.f;
            acc[i][j][2] = 0.f; acc[i][j][3] = 0.f;
        }

    const int K  = Dn;
    const int r0 = tid >> 2;                              // staged row 0..63
    const int sc = ((tid & 3) ^ ((tid >> 3) & 3)) * 8;    // pre-swizzled chunk
    const short* Ar0 = A  + (size_t)(m0  + r0)      * K + sc;
    const short* Br0 = Wp + (size_t)(nl0 + r0)      * K + sc;
    const short* Br1 = Wp + (size_t)(nl0 + r0 + 64) * K + sc;

    const int cA = (quad ^ ((l16 >> 1) & 3)) * 8;         // swizzled read chunk

    for (int k0 = 0; k0 < K; k0 += 32) {
        __syncthreads();
        GLOAD(Ar0 + k0, &As[wave * 512]);
        GLOAD(Br0 + k0, &Bs[wave * 512]);
        GLOAD(Br1 + k0, &Bs[2048 + wave * 512]);
        __syncthreads();

        frag16 a[2], b[4];
        #pragma unroll
        for (int mi = 0; mi < 2; mi++)
            a[mi] = *(const frag16*)&As[(wm * 32 + mi * 16 + l16) * 32 + cA];
        #pragma unroll
        for (int ni = 0; ni < 4; ni++)
            b[ni] = *(const frag16*)&Bs[(wn * 64 + ni * 16 + l16) * 32 + cA];
        #pragma unroll
        for (int mi = 0; mi < 2; mi++)
            #pragma unroll
            for (int ni = 0; ni < 4; ni++)
                acc[mi][ni] = __builtin_amdgcn_mfma_f32_16x16x32_f16(
                    a[mi], b[ni], acc[mi][ni], 0, 0, 0);
    }

    const float QSCALE = 0.125f * 1.44269504088896340736f;

    #pragma unroll
    for (int mi = 0; mi < 2; mi++) {
        #pragma unroll
        for (int ni = 0; ni < 4; ni++) {
            int nl = nl0 + wn * 64 + ni * 16 + l16;
            float bv = bias[nl];
            #pragma unroll
            for (int r = 0; r < 4; r++) {
                int m = m0 + wm * 32 + mi * 16 + quad * 4 + r;
                float v = acc[mi][ni][r] + bv;
                int b  = m >> 11, s = m & (Sn - 1);
                int h  = nl >> 6, dk = nl & 63;
                if (widx == 0)
                    Qb[((size_t)(b * Hn + h) * Sn + s) * DKn + dk] = f2bf(v * QSCALE);
                else if (widx == 1)
                    Kb[((size_t)(b * Hn + h) * Sn + s) * DKn + dk] = f2bf(v);
                else {
                    float mv = (float)mask[b * Sn + s];
                    Vtb[((size_t)(b * Hn + h) * DKn + dk) * Sn + s] = f2bf(v * mv);
                }
            }
        }
    }
}

// ---------------- Out GEMM: fp16, 64x64 tile, 1024 blocks, fp32 out ---------
__global__ __launch_bounds__(256) void gemm_out(
    const short* __restrict__ A, const short* __restrict__ Wp,
    const float* __restrict__ bias, float* __restrict__ outf)
{
    __shared__ __align__(16) short As[64 * 32];     // 4 KB
    __shared__ __align__(16) short Bs[64 * 32];     // 4 KB

    const int tid  = threadIdx.x;
    const int wave = tid >> 6;
    const int lane = tid & 63;
    const int quad = lane >> 4;
    const int l16  = lane & 15;
    const int wm   = wave >> 1;
    const int wn   = wave & 1;

    const int m0 = blockIdx.y * 64;
    const int n0 = blockIdx.x * 64;

    f4 acc[2][2];
    #pragma unroll
    for (int i = 0; i < 2; i++)
        #pragma unroll
        for (int j = 0; j < 2; j++) {
            acc[i][j][0] = 0.f; acc[i][j][1] = 0.f;
            acc[i][j][2] = 0.f; acc[i][j][3] = 0.f;
        }

    const int K  = Dn;
    const int r0 = tid >> 2;
    const int sc = ((tid & 3) ^ ((tid >> 3) & 3)) * 8;
    const short* Ao0 = A  + (size_t)(m0 + r0) * K + sc;
    const short* Bo0 = Wp + (size_t)(n0 + r0) * K + sc;

    const int cA = (quad ^ ((l16 >> 1) & 3)) * 8;

    for (int k0 = 0; k0 < K; k0 += 32) {
        __syncthreads();
        GLOAD(Ao0 + k0, &As[wave * 512]);
        GLOAD(Bo0 + k0, &Bs[wave * 512]);
        __syncthreads();

        frag16 a[2], b[2];
        #pragma unroll
        for (int mi = 0; mi < 2; mi++)
            a[mi] = *(const frag16*)&As[(wm * 32 + mi * 16 + l16) * 32 + cA];
        #pragma unroll
        for (int ni = 0; ni < 2; ni++)
            b[ni] = *(const frag16*)&Bs[(wn * 32 + ni * 16 + l16) * 32 + cA];
        #pragma unroll
        for (int mi = 0; mi < 2; mi++)
            #pragma unroll
            for (int ni = 0; ni < 2; ni++)
                acc[mi][ni] = __builtin_amdgcn_mfma_f32_16x16x32_f16(
                    a[mi], b[ni], acc[mi][ni], 0, 0, 0);
    }

    #pragma unroll
    for (int mi = 0; mi < 2; mi++) {
        #pragma unroll
        for (int ni = 0; ni < 2; ni++) {
            int nl = n0 + wn * 32 + ni * 16 + l16;
            float bv = bias[nl];
            #pragma unroll
            for (int r = 0; r < 4; r++) {
                int m = m0 + wm * 32 + mi * 16 + quad * 4 + r;
                outf[(size_t)m * Dn + nl] = acc[mi][ni][r] + bv;
            }
        }
    }
}

// ---------------- Flash attention: split-K x2, raw v_exp_f32 softmax --------
#define LP  72

__global__ __launch_bounds__(256) void attn_mfma(
    const short* __restrict__ Qb, const short* __restrict__ Kb,
    const short* __restrict__ Vtb, const short* __restrict__ mfb,
    float* __restrict__ ctxp0, float* __restrict__ ctxp1,
    float* __restrict__ lp)
{
    __shared__ __align__(16) short Ks[64 * 64];
    __shared__ __align__(16) short Vs[64 * 64];
    __shared__ short Ps[4][32 * LP];
    __shared__ __align__(16) short mfs[64];

    const int tid  = threadIdx.x;
    const int wave = tid >> 6;
    const int lane = tid & 63;
    const int quad = lane >> 4;
    const int l16  = lane & 15;

    const int split = blockIdx.x & 1;
    const int rest  = blockIdx.x >> 1;
    const int qt  = rest & 15;
    const int bhh = rest >> 4;
    const int b   = bhh >> 4;
    const int h   = bhh & 15;

    fragb qf[2][2];
    #pragma unroll
    for (int w = 0; w < 2; w++) {
        int qrow = qt * 128 + wave * 32 + w * 16 + l16;
        const short* qptr = Qb + ((size_t)bhh * Sn + qrow) * DKn + quad * 8;
        qf[w][0] = *(const fragb*)(qptr);
        qf[w][1] = *(const fragb*)(qptr + 32);
    }

    f4 ctx[2][4];
    #pragma unroll
    for (int w = 0; w < 2; w++)
        #pragma unroll
        for (int dt = 0; dt < 4; dt++) {
            ctx[w][dt][0] = 0.f; ctx[w][dt][1] = 0.f;
            ctx[w][dt][2] = 0.f; ctx[w][dt][3] = 0.f;
        }
    f4 lacc[2];
    lacc[0][0] = 0.f; lacc[0][1] = 0.f; lacc[0][2] = 0.f; lacc[0][3] = 0.f;
    lacc[1] = lacc[0];

    const int lr = lane >> 3;
    const int sc = ((lane & 7) ^ lr) * 8;
    const short* Kg = Kb  + (size_t)bhh * Sn * DKn;
    const short* Vg = Vtb + (size_t)bhh * DKn * Sn;
    const short* mg = mfb + (size_t)b * Sn;

    const short* Ksrc = Kg + (size_t)(wave * 16 + lr) * DKn + sc;
    const short* Vsrc = Vg + (size_t)(wave * 16 + lr) * Sn + sc;

    const int c0 = ((quad ^ (l16 & 7)) * 8);

    const int kt0 = split * 16;
    for (int kt = kt0; kt < kt0 + 16; kt++) {
        __syncthreads();
        GLOAD(Ksrc + (size_t)kt * 4096,             &Ks[(wave * 16) * 64]);
        GLOAD(Ksrc + (size_t)kt * 4096 + 8 * DKn,   &Ks[(wave * 16 + 8) * 64]);
        GLOAD(Vsrc + (size_t)kt * 64,               &Vs[(wave * 16) * 64]);
        GLOAD(Vsrc + (size_t)kt * 64 + 8 * Sn,      &Vs[(wave * 16 + 8) * 64]);
        if (tid < 8)
            *(uint4*)&mfs[tid * 8] = *(const uint4*)(mg + kt * 64 + tid * 8);
        __syncthreads();

        #pragma unroll
        for (int t = 0; t < 4; t++) {
            fragb k0 = *(const fragb*)&Ks[(t * 16 + l16) * 64 + c0];
            fragb k1 = *(const fragb*)&Ks[(t * 16 + l16) * 64 + (c0 ^ 32)];
            #pragma unroll
            for (int w = 0; w < 2; w++) {
                f4 a; a[0] = 0.f; a[1] = 0.f; a[2] = 0.f; a[3] = 0.f;
                a = __builtin_amdgcn_mfma_f32_16x16x32_bf16(k0, qf[w][0], a, 0, 0, 0);
                a = __builtin_amdgcn_mfma_f32_16x16x32_bf16(k1, qf[w][1], a, 0, 0, 0);
                // raw v_exp_f32 (log2e folded into Q): 1 instr vs OCML's ~8
                unsigned u0 = __float_as_uint(__builtin_amdgcn_exp2f(a[0]));
                unsigned u1 = __float_as_uint(__builtin_amdgcn_exp2f(a[1]));
                unsigned u2 = __float_as_uint(__builtin_amdgcn_exp2f(a[2]));
                unsigned u3 = __float_as_uint(__builtin_amdgcn_exp2f(a[3]));
                uint2 pw;
                pw.x = __builtin_amdgcn_perm(u1, u0, 0x07060302u);
                pw.y = __builtin_amdgcn_perm(u3, u2, 0x07060302u);
                *(uint2*)&Ps[wave][(w * 16 + l16) * LP + 16 * t + quad * 4] = pw;
            }
        }

        fragb p[2][2];
        #pragma unroll
        for (int w = 0; w < 2; w++) {
            p[w][0] = *(const fragb*)&Ps[wave][(w * 16 + l16) * LP + quad * 8];
            p[w][1] = *(const fragb*)&Ps[wave][(w * 16 + l16) * LP + quad * 8 + 32];
        }
        fragb m0 = *(const fragb*)&mfs[quad * 8];
        fragb m1 = *(const fragb*)&mfs[quad * 8 + 32];
        #pragma unroll
        for (int w = 0; w < 2; w++) {
            lacc[w] = __builtin_amdgcn_mfma_f32_16x16x32_bf16(p[w][0], m0, lacc[w], 0, 0, 0);
            lacc[w] = __builtin_amdgcn_mfma_f32_16x16x32_bf16(p[w][1], m1, lacc[w], 0, 0, 0);
        }
        #pragma unroll
        for (int dt = 0; dt < 4; dt++) {
            fragb v0 = *(const fragb*)&Vs[(dt * 16 + l16) * 64 + c0];
            fragb v1 = *(const fragb*)&Vs[(dt * 16 + l16) * 64 + (c0 ^ 32)];
            #pragma unroll
            for (int w = 0; w < 2; w++) {
                ctx[w][dt] = __builtin_amdgcn_mfma_f32_16x16x32_bf16(p[w][0], v0, ctx[w][dt], 0, 0, 0);
                ctx[w][dt] = __builtin_amdgcn_mfma_f32_16x16x32_bf16(p[w][1], v1, ctx[w][dt], 0, 0, 0);
            }
        }
    }

    float* cp  = split ? ctxp1 : ctxp0;
    float* lpp = lp + (size_t)split * BHS;
    #pragma unroll
    for (int w = 0; w < 2; w++)
        #pragma unroll
        for (int r = 0; r < 4; r++) {
            int row = qt * 128 + wave * 32 + w * 16 + quad * 4 + r;
            if (l16 == 0) lpp[(size_t)bhh * Sn + row] = lacc[w][r];
            #pragma unroll
            for (int dt = 0; dt < 4; dt++)
                cp[((size_t)(b * Sn + row)) * Dn + h * DKn + dt * 16 + l16] =
                    ctx[w][dt][r];
        }
}

// ---------------- reduce: merge split partials, normalize, emit fp16 --------
__global__ __launch_bounds__(256) void reduce_ctx(
    const float* __restrict__ c0, const float* __restrict__ c1,
    const float* __restrict__ lp, short* __restrict__ Ch)
{
    int i4 = blockIdx.x * 256 + threadIdx.x;
    int e    = i4 << 2;
    int brow = e >> 10;
    int d    = e & 1023;
    int b    = brow >> 11;
    int row  = brow & (Sn - 1);
    int h    = d >> 6;
    size_t li = (size_t)(b * Hn + h) * Sn + row;
    float l = lp[li] + lp[BHS + li];
    float inv = 1.f / l;
    float4 v0 = ((const float4*)c0)[i4];
    float4 v1 = ((const float4*)c1)[i4];
    ushort4 o;
    o.x = f2h((v0.x + v1.x) * inv);
    o.y = f2h((v0.y + v1.y) * inv);
    o.z = f2h((v0.z + v1.z) * inv);
    o.w = f2h((v0.w + v1.w) * inv);
    ((ushort4*)Ch)[i4] = o;
}

// ---------------- launch ----------------
extern "C" void kernel_launch(void* const* d_in, const int* in_sizes, int n_in,
                              void* d_out, int out_size, void* d_ws, size_t ws_size,
                              hipStream_t stream) {
    const float* x    = (const float*)d_in[0];
    const int*   mask = (const int*)d_in[1];
    const float* Wq   = (const float*)d_in[2];
    const float* bq   = (const float*)d_in[3];
    const float* Wk   = (const float*)d_in[4];
    const float* bk   = (const float*)d_in[5];
    const float* Wv   = (const float*)d_in[6];
    const float* bv   = (const float*)d_in[7];
    const float* Wo   = (const float*)d_in[8];
    const float* bo   = (const float*)d_in[9];
    float* out = (float*)d_out;

    char* ws = (char*)d_ws;
    const size_t MB = 1024u * 1024u;
    short* xh    = (short*)(ws + 0 * MB);    // 8 MB fp16 (dead after QKV)
    short* Wqh   = (short*)(ws + 8 * MB);
    short* Wkh   = (short*)(ws + 10 * MB);
    short* Wvh   = (short*)(ws + 12 * MB);
    short* Qb    = (short*)(ws + 16 * MB);
    short* Kb    = (short*)(ws + 24 * MB);
    short* Vtb   = (short*)(ws + 32 * MB);
    float* ctxp0 = (float*)(ws + 0 * MB);    // overlays dead region
    float* ctxp1 = (float*)(ws + 40 * MB);
    short* Woh   = (short*)(ws + 56 * MB);
    float* lp    = (float*)(ws + 58 * MB);
    short* mfb   = (short*)(ws + 59 * MB);
    short* Ch    = (short*)(ws + 60 * MB);

    const int PRE = NF4 + (Bn * Sn) / 4;
    prep<<<(PRE + 255) / 256, 256, 0, stream>>>(
        x, Wq, Wk, Wv, Wo, mask, xh, Wqh, Wkh, Wvh, Woh, mfb);

    gemm_qkv<<<dim3(24, 64), 256, 0, stream>>>(
        xh, Wqh, bq, Wkh, bk, Wvh, bv, mask, Qb, Kb, Vtb);

    attn_mfma<<<dim3(Bn * Hn * (Sn / 128) * 2), 256, 0, stream>>>(
        Qb, Kb, Vtb, mfb, ctxp0, ctxp1, lp);

    reduce_ctx<<<dim3(NX / 4 / 256), 256, 0, stream>>>(ctxp0, ctxp1, lp, Ch);

    gemm_out<<<dim3(16, 64), 256, 0, stream>>>(Ch, Woh, bo, out);
}